// Round 1
// baseline (76.954 us; speedup 1.0000x reference)
//
#include <hip/hip_runtime.h>

// PEPS 6x6 amplitude, D=3, B samples.
// T shape (6,6,3,3,3,3,2,2,2,2,2) fp32; x shape (B,36) int32 in {0,1}.
// Per sample: boundary-vector contraction. v[729] over u-composite, apply
// column MPO x=0..5 via y-sweep with 2187-float intermediates in LDS.
// Boundary legs pinned to index 0 (u@x=0 via delta init, l@y=0, r@y=5,
// d@x=5 via reading v[0] at the end).

constexpr int SITE_STRIDE = 81 * 32; // 2592 floats per site in T

__global__ __launch_bounds__(256)
void peps_amp_kernel(const int* __restrict__ xs, const float* __restrict__ T,
                     float* __restrict__ out) {
    __shared__ float A[36 * 81];     // sliced site tensors, perm = ((u*3+d)*3+l)*3+r
    __shared__ float V[729];         // boundary vector (u-composite, u0 major)
    __shared__ float Wbuf[2][2187];  // ping-pong sweep intermediates
    __shared__ int sg[36];
    __shared__ int sidx[36];

    const int b = blockIdx.x;
    const int t = threadIdx.x;

    if (t < 36) sg[t] = xs[b * 36 + t];
    __syncthreads();
    if (t < 36) {
        const int i = t / 6, j = t % 6;
        const int p  = sg[t];
        const int pu = (i > 0) ? sg[t - 6] : 0;
        const int pd = (i < 5) ? sg[t + 6] : 0;
        const int pl = (j > 0) ? sg[t - 1] : 0;
        const int pr = (j < 5) ? sg[t + 1] : 0;
        sidx[t] = (((p * 2 + pu) * 2 + pd) * 2 + pl) * 2 + pr;
    }
    __syncthreads();
    // Gather all site tensors: A[site][perm] = T[site*2592 + perm*32 + sidx]
    for (int idx = t; idx < 36 * 81; idx += 256) {
        const int site = idx / 81;
        const int perm = idx - site * 81;
        A[idx] = T[site * SITE_STRIDE + perm * 32 + sidx[site]];
    }
    // v init: delta at 0 (pins u-composite of column 0 to 0)
    for (int idx = t; idx < 729; idx += 256) V[idx] = (idx == 0) ? 1.0f : 0.0f;
    __syncthreads();

    for (int xc = 0; xc < 6; ++xc) {
        const float* Arow = &A[xc * 6 * 81];

        // ---- y = 0 (l pinned to 0): V[729] -> Wbuf[0][2187]
        // W0[(d*3+r)*243 + ur] = sum_u V[u*243+ur] * A0[u*27 + d*9 + r]
        if (t < 243) {
            const float v0 = V[t], v1 = V[243 + t], v2 = V[486 + t];
            const float* A0 = Arow;
            #pragma unroll
            for (int d = 0; d < 3; ++d)
                #pragma unroll
                for (int r = 0; r < 3; ++r) {
                    Wbuf[0][(d * 3 + r) * 243 + t] =
                        v0 * A0[d * 9 + r] +
                        v1 * A0[27 + d * 9 + r] +
                        v2 * A0[54 + d * 9 + r];
                }
        }
        __syncthreads();

        // ---- y = 1..4 generic: W[(dc*3+l)*3P + u*P + ur] -> W[((dc*3+d)*3+r)*P + ur]
        int cur = 0;
        int P = 81;
        #pragma unroll
        for (int y = 1; y <= 4; ++y) {
            const float* Ay = Arow + y * 81;
            const float* Wp = Wbuf[cur];
            float* Wn = Wbuf[cur ^ 1];
            if (t < 243) {
                const int dc = t / P;
                const int ur = t - dc * P;
                float wv[3][3];
                #pragma unroll
                for (int l = 0; l < 3; ++l)
                    #pragma unroll
                    for (int u = 0; u < 3; ++u)
                        wv[u][l] = Wp[(dc * 3 + l) * 3 * P + u * P + ur];
                #pragma unroll
                for (int d = 0; d < 3; ++d)
                    #pragma unroll
                    for (int r = 0; r < 3; ++r) {
                        float acc = 0.f;
                        #pragma unroll
                        for (int u = 0; u < 3; ++u)
                            #pragma unroll
                            for (int l = 0; l < 3; ++l)
                                acc += wv[u][l] * Ay[((u * 3 + d) * 3 + l) * 3 + r];
                        Wn[((dc * 3 + d) * 3 + r) * P + ur] = acc;
                    }
            }
            __syncthreads();
            cur ^= 1;
            P /= 3;
        }

        // ---- y = 5 (r pinned to 0): W[2187] -> V[729]
        // V[dc*3+d] = sum_{u,l} W[(dc*3+l)*3 + u] * A5[u*27 + d*9 + l*3]
        {
            const float* Ay = Arow + 5 * 81;
            const float* Wp = Wbuf[cur];
            if (t < 243) {
                float wv[3][3];
                #pragma unroll
                for (int l = 0; l < 3; ++l)
                    #pragma unroll
                    for (int u = 0; u < 3; ++u)
                        wv[u][l] = Wp[(t * 3 + l) * 3 + u];
                #pragma unroll
                for (int d = 0; d < 3; ++d) {
                    float acc = 0.f;
                    #pragma unroll
                    for (int u = 0; u < 3; ++u)
                        #pragma unroll
                        for (int l = 0; l < 3; ++l)
                            acc += wv[u][l] * Ay[u * 27 + d * 9 + l * 3];
                    V[t * 3 + d] = acc;
                }
            }
        }
        __syncthreads();
    }

    if (t == 0) out[b] = V[0];
}

extern "C" void kernel_launch(void* const* d_in, const int* in_sizes, int n_in,
                              void* d_out, int out_size, void* d_ws, size_t ws_size,
                              hipStream_t stream) {
    const int* xs = (const int*)d_in[0];
    const float* T = (const float*)d_in[1];
    float* out = (float*)d_out;
    const int B = in_sizes[0] / 36;
    peps_amp_kernel<<<B, 256, 0, stream>>>(xs, T, out);
}

// Round 3
// 68.492 us; speedup vs baseline: 1.1236x; 1.1236x over previous
//
#include <hip/hip_runtime.h>

// PEPS 6x6 amplitude, D=3, B samples. Bidirectional boundary contraction:
// forward half (waves 0-3): v_f = e0^T M0 M1 M2 ; backward half (waves 4-7):
// v_b = M3 M4 M5 e0 ; amplitude = v_f . v_b. Boundary columns (x=0 / x=5)
// are computed directly as 3-vector chain products (u resp. d leg pinned
// to 0), interior columns via the 6-step y-sweep MPO application with
// 2187-float LDS intermediates. Backward sweep = forward sweep with the
// u/d strides of the site tensor swapped (apply M from the right).

constexpr int SITE_STRIDE = 81 * 32; // 2592 floats per site in T

__global__ __launch_bounds__(512)
void peps_amp_kernel(const int* __restrict__ xs, const float* __restrict__ T,
                     float* __restrict__ out) {
    __shared__ float A[36 * 81];      // sliced site tensors, perm = ((u*3+d)*3+l)*3+r
    __shared__ float Vsh[2][729];     // boundary vectors (fwd, bwd)
    __shared__ float Wsh[2][2][2187]; // per-half ping-pong sweep intermediates
    __shared__ float red[8];
    __shared__ int sg[36];
    __shared__ int sidx[36];

    const int b = blockIdx.x;
    const int t = threadIdx.x;
    const int half = t >> 8;   // 0 = forward (M0..M2), 1 = backward (M5..M3)
    const int lt = t & 255;

    if (t < 36) sg[t] = xs[b * 36 + t];
    __syncthreads();
    if (t < 36) {
        const int i = t / 6, j = t % 6;
        const int p  = sg[t];
        const int pu = (i > 0) ? sg[t - 6] : 0;
        const int pd = (i < 5) ? sg[t + 6] : 0;
        const int pl = (j > 0) ? sg[t - 1] : 0;
        const int pr = (j < 5) ? sg[t + 1] : 0;
        sidx[t] = (((p * 2 + pu) * 2 + pd) * 2 + pl) * 2 + pr;
    }
    __syncthreads();
    for (int idx = t; idx < 36 * 81; idx += 512) {
        const int site = idx / 81;
        const int perm = idx - site * 81;
        A[idx] = T[site * SITE_STRIDE + perm * 32 + sidx[site]];
    }
    __syncthreads();

    float* V  = Vsh[half];
    float* Wa = Wsh[half][0];
    float* Wb = Wsh[half][1];
    // A perm index = u*27 + d*9 + l*3 + r. Forward contracts u (SS=27) and
    // produces d (SO=9); backward contracts d (SS=9) and produces u (SO=27).
    const int SS = half ? 9 : 27;
    const int SO = half ? 27 : 9;

    // ---- specialized boundary column: x=0 (fwd, u pinned 0) / x=5 (bwd, d pinned 0)
    {
        const float* Arow = &A[(half ? 30 : 0) * 81];
        for (int k = lt; k < 729; k += 256) {
            int c[6];
            c[0] = k / 243;
            c[1] = (k / 81) % 3;
            c[2] = (k / 27) % 3;
            c[3] = (k / 9) % 3;
            c[4] = (k / 3) % 3;
            c[5] = k % 3;
            // y=0: l pinned 0
            float v0 = Arow[c[0] * SO + 0];
            float v1 = Arow[c[0] * SO + 1];
            float v2 = Arow[c[0] * SO + 2];
            #pragma unroll
            for (int y = 1; y <= 4; ++y) {
                const float* Ay = Arow + y * 81 + c[y] * SO;
                const float n0 = v0 * Ay[0] + v1 * Ay[3] + v2 * Ay[6];
                const float n1 = v0 * Ay[1] + v1 * Ay[4] + v2 * Ay[7];
                const float n2 = v0 * Ay[2] + v1 * Ay[5] + v2 * Ay[8];
                v0 = n0; v1 = n1; v2 = n2;
            }
            // y=5: r pinned 0
            const float* A5 = Arow + 5 * 81 + c[5] * SO;
            V[k] = v0 * A5[0] + v1 * A5[3] + v2 * A5[6];
        }
    }
    __syncthreads();

    // ---- two interior columns per half
    for (int cc = 0; cc < 2; ++cc) {
        const int xc = half ? (4 - cc) : (1 + cc);
        const float* Arow = &A[xc * 6 * 81];

        // y = 0 (l pinned 0): V[729] -> Wa[2187]
        if (lt < 243) {
            const float v0 = V[lt], v1 = V[243 + lt], v2 = V[486 + lt];
            const float* A0 = Arow;
            #pragma unroll
            for (int o = 0; o < 3; ++o)
                #pragma unroll
                for (int r = 0; r < 3; ++r) {
                    Wa[(o * 3 + r) * 243 + lt] =
                        v0 * A0[o * SO + r] +
                        v1 * A0[SS + o * SO + r] +
                        v2 * A0[2 * SS + o * SO + r];
                }
        }
        __syncthreads();

        // y = 1..4 generic
        int cur = 0;
        int P = 81;
        #pragma unroll
        for (int y = 1; y <= 4; ++y) {
            const float* Ay = Arow + y * 81;
            const float* Wp = cur ? Wb : Wa;
            float* Wn = cur ? Wa : Wb;
            if (lt < 243) {
                const int dc = lt / P;
                const int ur = lt - dc * P;
                float wv[3][3];
                #pragma unroll
                for (int l = 0; l < 3; ++l)
                    #pragma unroll
                    for (int s = 0; s < 3; ++s)
                        wv[s][l] = Wp[(dc * 3 + l) * 3 * P + s * P + ur];
                #pragma unroll
                for (int o = 0; o < 3; ++o)
                    #pragma unroll
                    for (int r = 0; r < 3; ++r) {
                        float acc = 0.f;
                        #pragma unroll
                        for (int s = 0; s < 3; ++s)
                            #pragma unroll
                            for (int l = 0; l < 3; ++l)
                                acc += wv[s][l] * Ay[s * SS + o * SO + l * 3 + r];
                        Wn[((dc * 3 + o) * 3 + r) * P + ur] = acc;
                    }
            }
            __syncthreads();
            cur ^= 1;
            P /= 3;
        }

        // y = 5 (r pinned 0): W[2187] -> V[729]
        {
            const float* Ay = Arow + 5 * 81;
            const float* Wp = cur ? Wb : Wa;
            if (lt < 243) {
                float wv[3][3];
                #pragma unroll
                for (int l = 0; l < 3; ++l)
                    #pragma unroll
                    for (int s = 0; s < 3; ++s)
                        wv[s][l] = Wp[(lt * 3 + l) * 3 + s];
                #pragma unroll
                for (int o = 0; o < 3; ++o) {
                    float acc = 0.f;
                    #pragma unroll
                    for (int s = 0; s < 3; ++s)
                        #pragma unroll
                        for (int l = 0; l < 3; ++l)
                            acc += wv[s][l] * Ay[s * SS + o * SO + l * 3];
                    V[lt * 3 + o] = acc;
                }
            }
        }
        __syncthreads();
    }

    // ---- amplitude = Vf . Vb
    float partial = 0.f;
    for (int i = t; i < 729; i += 512) partial += Vsh[0][i] * Vsh[1][i];
    #pragma unroll
    for (int off = 32; off > 0; off >>= 1) partial += __shfl_down(partial, off);
    if ((t & 63) == 0) red[t >> 6] = partial;
    __syncthreads();
    if (t == 0) {
        float s = 0.f;
        #pragma unroll
        for (int w = 0; w < 8; ++w) s += red[w];
        out[b] = s;
    }
}

extern "C" void kernel_launch(void* const* d_in, const int* in_sizes, int n_in,
                              void* d_out, int out_size, void* d_ws, size_t ws_size,
                              hipStream_t stream) {
    const int* xs = (const int*)d_in[0];
    const float* T = (const float*)d_in[1];
    float* out = (float*)d_out;
    const int B = in_sizes[0] / 36;
    peps_amp_kernel<<<B, 512, 0, stream>>>(xs, T, out);
}